// Round 8
// baseline (3120.110 us; speedup 1.0000x reference)
//
#include <hip/hip_runtime.h>

// LSTM: SEQ=256, INPUT_DIM=1, HIDDEN=1024, NUM_CLASSES=10, BATCH=512, fp32 in/out.
// Persistent kernel, 256 wgs x 256 threads, 1 wg/CU. wg (r,c): h-slice [32r,32r+32),
// batch-slice [64c,64c+64).
// K-SPLIT compute: wave w computes ALL 4 row-tiles (32h x 4 gates) over k-quarter
//   [256w,256w+256) -> each staged B fragment read once, reused by 8 MFMAs.
//   Partials exchanged via LDS with ONE intra-wg s_barrier; wave w owns tile w's output.
// SYNC (round-6 proven, unchanged): ht = plain stores + sc0 global_load_lds within the
//   XCD's L2 (fast path; XCD-uniformity verified via HW_REG_XCC_ID, sc1 fallback);
//   group barrier = per-wg sc1 flag stores + wave0 parallel poll + __syncthreads relay.

#define HID  1024
#define SEQL 256

typedef __bf16 bf16x8 __attribute__((ext_vector_type(8)));
typedef float  f32x16 __attribute__((ext_vector_type(16)));
typedef unsigned u32x4 __attribute__((ext_vector_type(4)));

#define AS1 __attribute__((address_space(1)))
#define AS3 __attribute__((address_space(3)))
#define MFMA __builtin_amdgcn_mfma_f32_32x32x16_bf16

__device__ __forceinline__ float fast_sigmoid(float v) {
    float e = __expf(-v);
    return 1.0f / (1.0f + e);
}
__device__ __forceinline__ float fast_tanh(float v) {
    float e = __expf(2.0f * v);
    return 1.0f - 2.0f / (e + 1.0f);
}
__device__ __forceinline__ unsigned pk2bf(float a, float b) {
    unsigned short ua = __builtin_bit_cast(unsigned short, (__bf16)a);
    unsigned short ub = __builtin_bit_cast(unsigned short, (__bf16)b);
    return (unsigned)ua | ((unsigned)ub << 16);
}
__device__ __forceinline__ float bfhi(unsigned u) { return __builtin_bit_cast(float, u & 0xFFFF0000u); }
__device__ __forceinline__ float bflo(unsigned u) { return __builtin_bit_cast(float, u << 16); }

__device__ __forceinline__ void store_sc1(unsigned* p, unsigned v) {
    asm volatile("global_store_dword %0, %1, off sc1" :: "v"(p), "v"(v) : "memory");
}
// device-scope (sc1) 16B load — coherent across XCDs
__device__ __forceinline__ u32x4 load16_sc1(const void* p) {
    u32x4 r;
    asm volatile("global_load_dwordx4 %0, %1, off sc1\n\t"
                 "s_waitcnt vmcnt(0)" : "=v"(r) : "v"(p) : "memory");
    return r;
}
// XCD-scope (sc0) 16B load — bypasses L1, served by this XCD's L2
__device__ __forceinline__ u32x4 load16_sc0(const void* p) {
    u32x4 r;
    asm volatile("global_load_dwordx4 %0, %1, off sc0\n\t"
                 "s_waitcnt vmcnt(0)" : "=v"(r) : "v"(p) : "memory");
    return r;
}

// sync region: [0..511] step flags (8 groups x 64 stride), [512..767] xcd slots
__global__ __launch_bounds__(256) void lstm_init(unsigned* sync, float* out) {
    int idx = blockIdx.x * 256 + threadIdx.x;          // 5120 threads
    if (idx < 768) store_sc1(sync + idx, 0u);          // sc1: no stale L2 copies
    if (idx < 5120) out[idx] = 0.05f;                  // sentinel, overwritten by lstm_main
}

__global__ __attribute__((amdgpu_flat_work_group_size(256, 256), amdgpu_waves_per_eu(1, 1)))
void lstm_main(
    const float* __restrict__ x,
    const float* __restrict__ Wgx, const float* __restrict__ Wgh, const float* __restrict__ bg,
    const float* __restrict__ Wix, const float* __restrict__ Wih, const float* __restrict__ bi,
    const float* __restrict__ Wfx, const float* __restrict__ Wfh, const float* __restrict__ bf_,
    const float* __restrict__ Wox, const float* __restrict__ Woh, const float* __restrict__ bo,
    const float* __restrict__ Wph, const float* __restrict__ bp,
    float* __restrict__ out,
    unsigned short* __restrict__ htA, unsigned short* __restrict__ htB,
    unsigned* __restrict__ sync)
{
    // 128 KiB: per wave w, region [w*2048, (w+1)*2048) uint4:
    //   staging: its k-quarter of B = 32 pairs x 64 lanes x 16B = 2048 uint4
    //   partial buffers (after KSTEPs consume staging): 6 x [4][64] uint4 in [0,1536)
    extern __shared__ uint4 ldsB[];

    const int tid = threadIdx.x;
    const int w   = tid >> 6;
    const int l   = tid & 63;
    const int l31 = l & 31;
    const int h5  = l >> 5;
    const int gid = blockIdx.x;
    const int c   = gid & 7;         // batch group (64 batches) — XCD-aligned by round-robin
    const int r   = gid >> 3;        // h group (32 h)

    // ---- A fragments: 4 row-tiles x 16 ksteps (own k-quarter) = 64 x bf16x8 ----
    // tile tq covers h [(r<<5)+8tq,+8); A row m=l31: gate=m>>3, dh=l&7; k = w*256+kq*16+h5*8+e
    const int gate = l31 >> 3;
    const float* Wsel = (gate == 0) ? Wgh : (gate == 1) ? Wih : (gate == 2) ? Wfh : Woh;
    bf16x8 A[64];
#pragma unroll
    for (int tq = 0; tq < 4; ++tq) {
#pragma unroll
        for (int kq = 0; kq < 16; ++kq) {
            const float* p = Wsel + (unsigned)((r << 5) + (tq << 3) + (l & 7)) * HID
                                  + (w << 8) + (kq << 4) + (h5 << 3);
            float4 u0 = ((const float4*)p)[0], u1 = ((const float4*)p)[1];
            bf16x8 a;
            a[0] = (__bf16)u0.x; a[1] = (__bf16)u0.y; a[2] = (__bf16)u0.z; a[3] = (__bf16)u0.w;
            a[4] = (__bf16)u1.x; a[5] = (__bf16)u1.y; a[6] = (__bf16)u1.z; a[7] = (__bf16)u1.w;
            A[tq * 16 + kq] = a;
            __builtin_amdgcn_sched_barrier(0);
        }
    }

    // per-lane Wx/bias for tile w rows: acc reg j -> gate=j>>2, dh=(j&3)+4*h5
    float wx16[16], bs16[16];
    {
        const float* WxA[4] = {Wgx, Wix, Wfx, Wox};
        const float* bA[4]  = {bg, bi, bf_, bo};
#pragma unroll
        for (int j = 0; j < 16; ++j) {
            int g = j >> 2;
            int h = (r << 5) + (w << 3) + (j & 3) + (h5 << 2);
            wx16[j] = WxA[g][h];
            bs16[j] = bA[g][h];
        }
    }

    // ---- XCD-uniformity handshake (round-6 proven) ----
    unsigned xcd;
    asm volatile("s_getreg_b32 %0, hwreg(HW_REG_XCC_ID)" : "=s"(xcd));
    unsigned* xslot = sync + 512;
    if (tid == 0) store_sc1(xslot + gid, xcd + 1u);
    bool fast;
    {
        const unsigned* sp = xslot + c + (l31 << 3);
        unsigned sv;
        while (true) {
            sv = __hip_atomic_load(sp, __ATOMIC_RELAXED, __HIP_MEMORY_SCOPE_AGENT);
            if (__ballot(sv >= 1u && sv <= 8u) == ~0ull) break;
            __builtin_amdgcn_s_sleep(1);
        }
        fast = (__ballot(sv == xcd + 1u) == ~0ull);
    }

    f32x16 Z;
#pragma unroll
    for (int i = 0; i < 16; ++i) Z[i] = 0.f;

    float ct[8];
#pragma unroll
    for (int i = 0; i < 8; ++i) ct[i] = 0.f;

    const unsigned short* htR = htA;
    unsigned short*       htW = htB;
    unsigned* gflags = sync + (c << 6);
    const float* xrow0 = x + (unsigned)((c << 6) + l31) * SEQL;
    const float* xrow1 = x + (unsigned)((c << 6) + 32 + l31) * SEQL;
    float xv0 = xrow0[0], xv1 = xrow1[0];

#define KSTEP(KQ) do { \
    uint4 r0 = ldsB[(w << 11) + ((KQ) << 7) + l]; \
    uint4 r1 = ldsB[(w << 11) + ((KQ) << 7) + 64 + l]; \
    bf16x8 b0 = __builtin_bit_cast(bf16x8, r0); \
    bf16x8 b1 = __builtin_bit_cast(bf16x8, r1); \
    acc00 = MFMA(A[(KQ)],      b0, acc00, 0,0,0); acc01 = MFMA(A[(KQ)],      b1, acc01, 0,0,0); \
    acc10 = MFMA(A[16 + (KQ)], b0, acc10, 0,0,0); acc11 = MFMA(A[16 + (KQ)], b1, acc11, 0,0,0); \
    acc20 = MFMA(A[32 + (KQ)], b0, acc20, 0,0,0); acc21 = MFMA(A[32 + (KQ)], b1, acc21, 0,0,0); \
    acc30 = MFMA(A[48 + (KQ)], b0, acc30, 0,0,0); acc31 = MFMA(A[48 + (KQ)], b1, acc31, 0,0,0); \
} while (0)

#define PWR4(ACC, POS, NT) do { \
    int bb = (w << 11) + ((((POS) << 1) + (NT)) << 8) + l; \
    _Pragma("unroll") for (int j = 0; j < 4; ++j) { \
        float4 f = {ACC[4*j], ACC[4*j+1], ACC[4*j+2], ACC[4*j+3]}; \
        ldsB[bb + (j << 6)] = __builtin_bit_cast(uint4, f); } \
} while (0)

#define PRD4(S, V, POS, NT) do { \
    int bb = ((V) << 11) + ((((POS) << 1) + (NT)) << 8) + l; \
    _Pragma("unroll") for (int j = 0; j < 4; ++j) { \
        float4 f = __builtin_bit_cast(float4, ldsB[bb + (j << 6)]); \
        S[4*j] += f.x; S[4*j+1] += f.y; S[4*j+2] += f.z; S[4*j+3] += f.w; } \
} while (0)

#define ACT(S, NT) do { \
    float xvn = (NT) ? xv1 : xv0; \
    _Pragma("unroll") for (int d = 0; d < 4; ++d) { \
        float ag = S[d]      + wx16[d] * xvn      + bs16[d]; \
        float ai = S[4 + d]  + wx16[4 + d] * xvn  + bs16[4 + d]; \
        float af = S[8 + d]  + wx16[8 + d] * xvn  + bs16[8 + d]; \
        float ao = S[12 + d] + wx16[12 + d] * xvn + bs16[12 + d]; \
        float g = fast_tanh(ag); float ii = fast_sigmoid(ai); \
        float ff = fast_sigmoid(af); float oo = fast_sigmoid(ao); \
        float cc = fmaf(ct[(NT) * 4 + d], ff, g * ii); \
        ct[(NT) * 4 + d] = cc; \
        htv[(NT) * 4 + d] = fast_tanh(cc) * oo; } \
} while (0)

#define FINW(ACC0, ACC1, V1, P1, V2, P2, V3, P3) do { \
    float s0[16]; \
    _Pragma("unroll") for (int j = 0; j < 16; ++j) s0[j] = ACC0[j]; \
    PRD4(s0, V1, P1, 0); PRD4(s0, V2, P2, 0); PRD4(s0, V3, P3, 0); \
    ACT(s0, 0); \
    float s1[16]; \
    _Pragma("unroll") for (int j = 0; j < 16; ++j) s1[j] = ACC1[j]; \
    PRD4(s1, V1, P1, 1); PRD4(s1, V2, P2, 1); PRD4(s1, V3, P3, 1); \
    ACT(s1, 1); \
} while (0)

    for (int t = 0; t < SEQL; ++t) {
        // prefetch x(t+1)
        int tn = (t + 1 < SEQL) ? t + 1 : t;
        float nx0, nx1;

        f32x16 acc00 = Z, acc01 = Z, acc10 = Z, acc11 = Z;
        f32x16 acc20 = Z, acc21 = Z, acc30 = Z, acc31 = Z;

        if (t > 0) {
            const unsigned short* gR = htR + (c << 16);
            // ---- stage own k-quarter: 32 x 1 KiB into own LDS region ----
            if (fast) {
#pragma unroll
                for (int j = 0; j < 32; ++j) {
                    const void* g = (const void*)(gR + ((w << 5) + j) * 512 + (l << 3));
                    __builtin_amdgcn_global_load_lds((const AS1 void*)g,
                        (AS3 void*)&ldsB[(w << 11) + (j << 6)], 16, 0, 0x1 /*sc0*/);
                }
            } else {
#pragma unroll
                for (int j = 0; j < 32; ++j) {
                    const void* g = (const void*)(gR + ((w << 5) + j) * 512 + (l << 3));
                    __builtin_amdgcn_global_load_lds((const AS1 void*)g,
                        (AS3 void*)&ldsB[(w << 11) + (j << 6)], 16, 0, 0x10 /*sc1*/);
                }
            }
            __builtin_amdgcn_sched_barrier(0);
            nx0 = xrow0[tn]; nx1 = xrow1[tn];
            __builtin_amdgcn_sched_barrier(0);

            // ---- K loop: 16 ksteps, per-wave counted drains (x loads stay in flight) ----
            asm volatile("s_waitcnt vmcnt(26)" ::: "memory");
            __builtin_amdgcn_sched_barrier(0);
            KSTEP(0); KSTEP(1); KSTEP(2); KSTEP(3);
            asm volatile("s_waitcnt vmcnt(18)" ::: "memory");
            __builtin_amdgcn_sched_barrier(0);
            KSTEP(4); KSTEP(5); KSTEP(6); KSTEP(7);
            asm volatile("s_waitcnt vmcnt(10)" ::: "memory");
            __builtin_amdgcn_sched_barrier(0);
            KSTEP(8); KSTEP(9); KSTEP(10); KSTEP(11);
            asm volatile("s_waitcnt vmcnt(2)" ::: "memory");
            __builtin_amdgcn_sched_barrier(0);
            KSTEP(12); KSTEP(13); KSTEP(14); KSTEP(15);
        } else {
            nx0 = xrow0[tn]; nx1 = xrow1[tn];
        }

        // ---- write partials for the 3 tiles != w into own region ----
        if (w == 0) {
            PWR4(acc10, 0, 0); PWR4(acc11, 0, 1);
            PWR4(acc20, 1, 0); PWR4(acc21, 1, 1);
            PWR4(acc30, 2, 0); PWR4(acc31, 2, 1);
        } else if (w == 1) {
            PWR4(acc00, 0, 0); PWR4(acc01, 0, 1);
            PWR4(acc20, 1, 0); PWR4(acc21, 1, 1);
            PWR4(acc30, 2, 0); PWR4(acc31, 2, 1);
        } else if (w == 2) {
            PWR4(acc00, 0, 0); PWR4(acc01, 0, 1);
            PWR4(acc10, 1, 0); PWR4(acc11, 1, 1);
            PWR4(acc30, 2, 0); PWR4(acc31, 2, 1);
        } else {
            PWR4(acc00, 0, 0); PWR4(acc01, 0, 1);
            PWR4(acc10, 1, 0); PWR4(acc11, 1, 1);
            PWR4(acc20, 2, 0); PWR4(acc21, 2, 1);
        }
        asm volatile("s_waitcnt lgkmcnt(0)" ::: "memory");
        __builtin_amdgcn_s_barrier();
        asm volatile("" ::: "memory");
        __builtin_amdgcn_sched_barrier(0);

        // ---- reduce own tile from 3 partners + Wx*x + bias -> activations ----
        float htv[8];
        if (w == 0)      FINW(acc00, acc01, 1, 0, 2, 0, 3, 0);
        else if (w == 1) FINW(acc10, acc11, 0, 0, 2, 1, 3, 1);
        else if (w == 2) FINW(acc20, acc21, 0, 1, 1, 1, 3, 2);
        else             FINW(acc30, acc31, 0, 2, 1, 2, 2, 2);

        // ---- store ht(t) as bf16 in B-fragment order ----
        {
            unsigned short* gW = htW + (c << 16);
            int kkw  = (r << 1) + (w >> 1);
            int slot = ((w & 1) << 5) + l31;
#pragma unroll
            for (int nt = 0; nt < 2; ++nt) {
                unsigned lo = pk2bf(htv[nt * 4 + 0], htv[nt * 4 + 1]);
                unsigned hi = pk2bf(htv[nt * 4 + 2], htv[nt * 4 + 3]);
                unsigned long long v = (unsigned long long)lo | ((unsigned long long)hi << 32);
                unsigned long long* dst =
                    (unsigned long long*)(gW + (((kkw * 2 + nt) * 64 + slot) * 8 + (h5 << 2)));
                if (fast) *dst = v;
                else __hip_atomic_store(dst, v, __ATOMIC_RELAXED, __HIP_MEMORY_SCOPE_AGENT);
            }
        }

        // ---- group barrier (round-6 proven relay) ----
        asm volatile("s_waitcnt vmcnt(0)" ::: "memory");   // ht stores ack'd
        __syncthreads();                                    // all 4 waves' stores ack'd
        unsigned target = (unsigned)(t + 1);
        if (tid == 0)
            __hip_atomic_store(&gflags[r], target, __ATOMIC_RELAXED, __HIP_MEMORY_SCOPE_AGENT);
        if (w == 0) {
            const unsigned* fp = gflags + l31;             // lanes l and l+32 read same flag
            while (true) {
                unsigned v = __hip_atomic_load(fp, __ATOMIC_RELAXED, __HIP_MEMORY_SCOPE_AGENT);
                if (__ballot(v >= target) == ~0ull) break;
                __builtin_amdgcn_s_sleep(1);
            }
        }
        __syncthreads();

        xv0 = nx0; xv1 = nx1;
        const unsigned short* tmp = htR; htR = htW; htW = (unsigned short*)tmp;
    }

    // ---- final projection: out[b][cls] = Wph[cls,:] . ht[:,b] + bp[cls] ----
    //   elem(h,b) at c*65536 + (h>>4)*1024 + ((b>>5)&1)*512 + ((h>>3)&1)*256 + (b&31)*8 + (h&7)
    // Lane l covers h in [16l,16l+16): two 16B loads at +0 and +256 elems.
    {
        const unsigned short* hfin = htR + (c << 16);
        for (int p = w; p < 20; p += 4) {
            int bloc = (r << 1) + (p / 10);
            int bb   = (c << 6) + bloc;
            int cls  = p % 10;
            const unsigned short* base = hfin + l * 1024 + ((bloc >> 5) & 1) * 512
                                              + (bloc & 31) * 8;
            u32x4 u0, u1;
            if (fast) { u0 = load16_sc0(base); u1 = load16_sc0(base + 256); }
            else      { u0 = load16_sc1(base); u1 = load16_sc1(base + 256); }
            const float* wp = Wph + (unsigned)cls * HID + (unsigned)l * 16;
            float s = 0.f;
#pragma unroll
            for (int e = 0; e < 4; ++e) {
                s = fmaf(wp[2 * e],         bflo(u0[e]), s);
                s = fmaf(wp[2 * e + 1],     bfhi(u0[e]), s);
                s = fmaf(wp[8 + 2 * e],     bflo(u1[e]), s);
                s = fmaf(wp[8 + 2 * e + 1], bfhi(u1[e]), s);
            }
#pragma unroll
            for (int off = 32; off > 0; off >>= 1) s += __shfl_xor(s, off, 64);
            if (l == 0) out[bb * 10 + cls] = s + bp[cls];
        }
    }
}

extern "C" void kernel_launch(void* const* d_in, const int* in_sizes, int n_in,
                              void* d_out, int out_size, void* d_ws, size_t ws_size,
                              hipStream_t stream) {
    const float* x   = (const float*)d_in[0];
    const float* Wgx = (const float*)d_in[1];
    const float* Wgh = (const float*)d_in[2];
    const float* bg  = (const float*)d_in[3];
    const float* Wix = (const float*)d_in[4];
    const float* Wih = (const float*)d_in[5];
    const float* bi  = (const float*)d_in[6];
    const float* Wfx = (const float*)d_in[7];
    const float* Wfh = (const float*)d_in[8];
    const float* bf_ = (const float*)d_in[9];
    const float* Wox = (const float*)d_in[10];
    const float* Woh = (const float*)d_in[11];
    const float* bo  = (const float*)d_in[12];
    const float* Wph = (const float*)d_in[13];
    const float* bp  = (const float*)d_in[14];
    float* out = (float*)d_out;

    char* ws = (char*)d_ws;
    unsigned short* htA = (unsigned short*)ws;                 // 1 MiB
    unsigned short* htB = (unsigned short*)(ws + (1 << 20));   // 1 MiB
    unsigned*      sync = (unsigned*)(ws + (2 << 20));         // 3 KiB: flags + xcd slots

    lstm_init<<<dim3(20), dim3(256), 0, stream>>>(sync, out);

    static int lds_set = 0;
    if (!lds_set) {
        hipFuncSetAttribute((const void*)lstm_main,
                            hipFuncAttributeMaxDynamicSharedMemorySize, 131072);
        lds_set = 1;
    }
    lstm_main<<<dim3(256), dim3(256), 131072, stream>>>(
        x, Wgx, Wgh, bg, Wix, Wih, bi, Wfx, Wfh, bf_,
        Wox, Woh, bo, Wph, bp, out, htA, htB, sync);
}